// Round 1
// baseline (2015.135 us; speedup 1.0000x reference)
//
#include <hip/hip_runtime.h>
#include <math.h>

#define NN 200000
#define NE 3200000
#define NF 128
#define NG 1000
#define KSEL 30
#define CCAT 97

// ---------------- degree / normalization ----------------
__global__ void k_init_deg(float* deg) {
    int n = blockIdx.x * 256 + threadIdx.x;
    if (n < NN) deg[n] = 1.0f;
}

__global__ void k_deg(const int* __restrict__ ei, float* deg) {
    int e = blockIdx.x * 256 + threadIdx.x;
    if (e >= NE) return;
    int s = ei[e], d = ei[NE + e];
    if (s != d) atomicAdd(&deg[d], 1.0f);
}

// degbuf holds deg on entry; on exit degbuf = 1/deg, inv_sqrt = 1/sqrt(deg)
__global__ void k_invs(float* degbuf, float* inv_sqrt) {
    int n = blockIdx.x * 256 + threadIdx.x;
    if (n >= NN) return;
    float d = degbuf[n];
    inv_sqrt[n] = 1.0f / sqrtf(d);
    degbuf[n] = 1.0f / d;
}

__global__ void k_coef(const int* __restrict__ ei, const float* __restrict__ inv_sqrt,
                       float* __restrict__ coef) {
    int e = blockIdx.x * 256 + threadIdx.x;
    if (e >= NE) return;
    int s = ei[e], d = ei[NE + e];
    coef[e] = (s != d) ? inv_sqrt[s] * inv_sqrt[d] : 0.0f;
}

// ---------------- dense matmul: Y[n,32] = X[n,K] @ W[K,32] ----------------
template <int K>
__global__ void k_mm(const float* __restrict__ X, const float* __restrict__ W,
                     float* __restrict__ Y, int n) {
    __shared__ float sx[8 * K];
    int row0 = blockIdx.x * 8;
    int tid = threadIdx.x;
    // rows row0..row0+7 are contiguous: sx[i] = X[row0*K + i]
    for (int i = tid; i < 8 * K; i += 256) {
        int row = row0 + i / K;
        sx[i] = (row < n) ? X[row0 * K + i] : 0.0f;
    }
    __syncthreads();
    int r = tid >> 5, c = tid & 31;
    int row = row0 + r;
    if (row >= n) return;
    float acc = 0.0f;
#pragma unroll 8
    for (int k = 0; k < K; k++) acc = fmaf(sx[r * K + k], W[k * 32 + c], acc);
    Y[row * 32 + c] = acc;
}

// out[n,c] = hw[n,c] * inv_deg[n] + b[c]   (self-loop term + bias)
__global__ void k_init_agg(const float* __restrict__ hw, const float* __restrict__ inv_deg,
                           const float* __restrict__ b, float* __restrict__ out) {
    int t = blockIdx.x * 256 + threadIdx.x;
    if (t >= NN * 32) return;
    int n = t >> 5, c = t & 31;
    out[t] = fmaf(hw[t], inv_deg[n], b[c]);
}

// 32 consecutive threads handle the 32 channels of one edge
__global__ void k_edge32(const int* __restrict__ ei, const float* __restrict__ coef,
                         const float* __restrict__ hw, float* __restrict__ out) {
    long long t = (long long)blockIdx.x * 256 + threadIdx.x;
    int e = (int)(t >> 5);
    int c = (int)(t & 31);
    if (e >= NE) return;
    float cf = coef[e];
    if (cf == 0.0f) return;
    int s = ei[e], d = ei[NE + e];
    atomicAdd(&out[d * 32 + c], hw[s * 32 + c] * cf);
}

__global__ void k_tanh(float* __restrict__ y, int len) {
    int t = blockIdx.x * 256 + threadIdx.x;
    if (t < len) y[t] = tanhf(y[t]);
}

// layer 4: hw4[n] = x3[n,:] . W4 ; x4[n] = hw4[n]*inv_deg[n] + b4
__global__ void k_mm4(const float* __restrict__ x3, const float* __restrict__ W4,
                      const float* __restrict__ b4, const float* __restrict__ inv_deg,
                      float* __restrict__ hw4, float* __restrict__ x4) {
    int n = blockIdx.x * 256 + threadIdx.x;
    if (n >= NN) return;
    const float4* xr = (const float4*)(x3 + n * 32);
    float acc = 0.0f;
#pragma unroll
    for (int q = 0; q < 8; q++) {
        float4 v = xr[q];
        acc = fmaf(v.x, W4[q * 4 + 0], acc);
        acc = fmaf(v.y, W4[q * 4 + 1], acc);
        acc = fmaf(v.z, W4[q * 4 + 2], acc);
        acc = fmaf(v.w, W4[q * 4 + 3], acc);
    }
    hw4[n] = acc;
    x4[n] = fmaf(acc, inv_deg[n], b4[0]);
}

__global__ void k_edge1(const int* __restrict__ ei, const float* __restrict__ coef,
                        const float* __restrict__ hw4, float* __restrict__ x4) {
    int e = blockIdx.x * 256 + threadIdx.x;
    if (e >= NE) return;
    float cf = coef[e];
    if (cf == 0.0f) return;
    atomicAdd(&x4[ei[NE + e]], hw4[ei[e]] * cf);
}

// ---------------- sort-pool ----------------
__global__ void k_hist(const int* __restrict__ batch, int* __restrict__ counts) {
    int n = blockIdx.x * 256 + threadIdx.x;
    if (n < NN) atomicAdd(&counts[batch[n]], 1);
}

__global__ void k_scan(const int* __restrict__ counts, int* __restrict__ starts) {
    __shared__ int s[1024];
    int tid = threadIdx.x;
    int c = (tid < NG) ? counts[tid] : 0;
    s[tid] = c;
    __syncthreads();
    for (int off = 1; off < 1024; off <<= 1) {
        int v = s[tid];
        int a = (tid >= off) ? s[tid - off] : 0;
        __syncthreads();
        s[tid] = v + a;
        __syncthreads();
    }
    if (tid < NG) starts[tid] = s[tid] - c;
}

__global__ void k_sortpool(const int* __restrict__ starts, const int* __restrict__ counts,
                           const float* __restrict__ x1, const float* __restrict__ x2,
                           const float* __restrict__ x3, const float* __restrict__ x4,
                           float* __restrict__ pooled) {
    __shared__ float keys[1024];
    __shared__ int sel[KSEL];
    int g = blockIdx.x;
    int tid = threadIdx.x;
    int start = starts[g];
    int cnt = counts[g];
    if (cnt > 1024) cnt = 1024;  // defensive; cannot happen statistically
    for (int i = tid; i < cnt; i += 256) keys[i] = x4[start + i];
    __syncthreads();
    for (int i = tid; i < cnt; i += 256) {
        float ki = keys[i];
        int rank = 0;
        for (int j = 0; j < cnt; j++) {
            float kj = keys[j];
            rank += (kj > ki) || (kj == ki && j < i);  // stable desc, matches lexsort
        }
        if (rank < KSEL) sel[rank] = start + i;
    }
    __syncthreads();
    int selcnt = cnt < KSEL ? cnt : KSEL;
    for (int t = tid; t < selcnt * CCAT; t += 256) {
        int r = t / CCAT, ch = t - r * CCAT;
        int node = sel[r];
        float v;
        if (ch < 32)      v = x1[node * 32 + ch];
        else if (ch < 64) v = x2[node * 32 + ch - 32];
        else if (ch < 96) v = x3[node * 32 + ch - 64];
        else              v = x4[node];
        pooled[g * (KSEL * CCAT) + t] = v;
    }
}

// ---------------- CNN + MLP head, one block per graph ----------------
__global__ void k_head(const float* __restrict__ pooled,
                       const float* __restrict__ w5, const float* __restrict__ b5,
                       const float* __restrict__ w6, const float* __restrict__ b6,
                       const float* __restrict__ fw1, const float* __restrict__ fb1,
                       const float* __restrict__ fw2, const float* __restrict__ fb2,
                       float* __restrict__ out) {
    __shared__ float sP[KSEL * CCAT];  // 2910
    __shared__ float s5[16 * 30];
    __shared__ float smp[16 * 15];
    __shared__ float sz[352];
    __shared__ float sh[128];
    __shared__ float sl[10];
    int g = blockIdx.x;
    int tid = threadIdx.x;
    for (int i = tid; i < KSEL * CCAT; i += 256) sP[i] = pooled[g * (KSEL * CCAT) + i];
    __syncthreads();
    // conv5: kernel 97 stride 97 -> out [16, 30], relu
    for (int t = tid; t < 16 * 30; t += 256) {
        int c = t / 30, j = t - c * 30;
        float acc = b5[c];
        for (int i = 0; i < CCAT; i++) acc = fmaf(sP[j * CCAT + i], w5[c * CCAT + i], acc);
        s5[c * 30 + j] = fmaxf(acc, 0.0f);
    }
    __syncthreads();
    // maxpool window 2 stride 2 -> [16, 15]
    for (int t = tid; t < 16 * 15; t += 256) {
        int c = t / 15, j = t - c * 15;
        smp[t] = fmaxf(s5[c * 30 + 2 * j], s5[c * 30 + 2 * j + 1]);
    }
    __syncthreads();
    // conv6: 16->32 ch, kernel 5 -> [32, 11], relu; flatten c*11+j
    for (int t = tid; t < 32 * 11; t += 256) {
        int c = t / 11, j = t - c * 11;
        float acc = b6[c];
        for (int ci = 0; ci < 16; ci++) {
#pragma unroll
            for (int k = 0; k < 5; k++)
                acc = fmaf(smp[ci * 15 + j + k], w6[(c * 16 + ci) * 5 + k], acc);
        }
        sz[t] = fmaxf(acc, 0.0f);
    }
    __syncthreads();
    // fc1: [352]->[128], relu
    if (tid < 128) {
        float acc = fb1[tid];
        for (int i = 0; i < 352; i++) acc = fmaf(sz[i], fw1[i * 128 + tid], acc);
        sh[tid] = fmaxf(acc, 0.0f);
    }
    __syncthreads();
    // fc2: [128]->[10]
    if (tid < 10) {
        float acc = fb2[tid];
        for (int i = 0; i < 128; i++) acc = fmaf(sh[i], fw2[i * 10 + tid], acc);
        sl[tid] = acc;
    }
    __syncthreads();
    if (tid < 10) {
        float m = -1e30f;
        for (int i = 0; i < 10; i++) m = fmaxf(m, sl[i]);
        float ssum = 0.0f;
        for (int i = 0; i < 10; i++) ssum += expf(sl[i] - m);
        out[g * 10 + tid] = sl[tid] - m - logf(ssum);
    }
}

extern "C" void kernel_launch(void* const* d_in, const int* in_sizes, int n_in,
                              void* d_out, int out_size, void* d_ws, size_t ws_size,
                              hipStream_t stream) {
    const float* x   = (const float*)d_in[0];
    const int*   ei  = (const int*)d_in[1];
    const int*   bat = (const int*)d_in[2];
    const float* W1  = (const float*)d_in[3];
    const float* b1  = (const float*)d_in[4];
    const float* W2  = (const float*)d_in[5];
    const float* b2  = (const float*)d_in[6];
    const float* W3  = (const float*)d_in[7];
    const float* b3  = (const float*)d_in[8];
    const float* W4  = (const float*)d_in[9];
    const float* b4  = (const float*)d_in[10];
    const float* w5  = (const float*)d_in[11];
    const float* b5  = (const float*)d_in[12];
    const float* w6  = (const float*)d_in[13];
    const float* b6  = (const float*)d_in[14];
    const float* fw1 = (const float*)d_in[15];
    const float* fb1 = (const float*)d_in[16];
    const float* fw2 = (const float*)d_in[17];
    const float* fb2 = (const float*)d_in[18];
    float* out = (float*)d_out;

    float* ws = (float*)d_ws;
    float* inv_sqrt = ws;                    // 200000
    float* inv_deg  = inv_sqrt + NN;         // 200000 (holds deg first)
    float* coef     = inv_deg + NN;          // 3200000
    float* hw       = coef + NE;             // 6400000 (also reused as hw4)
    float* x1       = hw + NN * 32;          // 6400000
    float* x2       = x1 + NN * 32;          // 6400000
    float* x3       = x2 + NN * 32;          // 6400000
    float* x4       = x3 + NN * 32;          // 200000
    float* pooled   = x4 + NN;               // 2910000
    int* counts     = (int*)(pooled + NG * KSEL * CCAT);  // 1024
    int* starts     = counts + 1024;         // 1024

    const int TB = 256;
    int gN   = (NN + TB - 1) / TB;           // 782
    int gE   = (NE + TB - 1) / TB;           // 12500
    int gNC  = (NN * 32 + TB - 1) / TB;      // 25000
    int gEC  = (int)(((long long)NE * 32 + TB - 1) / TB);  // 400000
    int gMM  = (NN + 7) / 8;                 // 25000

    // normalization
    k_init_deg<<<gN, TB, 0, stream>>>(inv_deg);
    k_deg<<<gE, TB, 0, stream>>>(ei, inv_deg);
    k_invs<<<gN, TB, 0, stream>>>(inv_deg, inv_sqrt);
    k_coef<<<gE, TB, 0, stream>>>(ei, inv_sqrt, coef);

    // layer 1 (K=128)
    k_mm<128><<<gMM, TB, 0, stream>>>(x, W1, hw, NN);
    k_init_agg<<<gNC, TB, 0, stream>>>(hw, inv_deg, b1, x1);
    k_edge32<<<gEC, TB, 0, stream>>>(ei, coef, hw, x1);
    k_tanh<<<gNC, TB, 0, stream>>>(x1, NN * 32);

    // layer 2
    k_mm<32><<<gMM, TB, 0, stream>>>(x1, W2, hw, NN);
    k_init_agg<<<gNC, TB, 0, stream>>>(hw, inv_deg, b2, x2);
    k_edge32<<<gEC, TB, 0, stream>>>(ei, coef, hw, x2);
    k_tanh<<<gNC, TB, 0, stream>>>(x2, NN * 32);

    // layer 3
    k_mm<32><<<gMM, TB, 0, stream>>>(x2, W3, hw, NN);
    k_init_agg<<<gNC, TB, 0, stream>>>(hw, inv_deg, b3, x3);
    k_edge32<<<gEC, TB, 0, stream>>>(ei, coef, hw, x3);
    k_tanh<<<gNC, TB, 0, stream>>>(x3, NN * 32);

    // layer 4 (out dim 1)
    k_mm4<<<gN, TB, 0, stream>>>(x3, W4, b4, inv_deg, hw, x4);
    k_edge1<<<gE, TB, 0, stream>>>(ei, coef, hw, x4);
    k_tanh<<<gN, TB, 0, stream>>>(x4, NN);

    // sort-pool
    hipMemsetAsync(counts, 0, 1024 * sizeof(int), stream);
    k_hist<<<gN, TB, 0, stream>>>(bat, counts);
    k_scan<<<1, 1024, 0, stream>>>(counts, starts);
    hipMemsetAsync(pooled, 0, (size_t)NG * KSEL * CCAT * sizeof(float), stream);
    k_sortpool<<<NG, TB, 0, stream>>>(starts, counts, x1, x2, x3, x4, pooled);

    // head
    k_head<<<NG, TB, 0, stream>>>(pooled, w5, b5, w6, b6, fw1, fb1, fw2, fb2, out);
}

// Round 2
// 1260.933 us; speedup vs baseline: 1.5981x; 1.5981x over previous
//
#include <hip/hip_runtime.h>
#include <math.h>

#define NN 200000
#define NE 3200000
#define NF 128
#define NG 1000
#define KSEL 30
#define CCAT 97
#define NPAD 200704      // 196 * 1024, padded node count for the scan
#define SCAN_BLKS 196

// ---------------- CSR build ----------------
__global__ void k_degcnt(const int* __restrict__ ei, int* __restrict__ rowcnt) {
    int e = blockIdx.x * 256 + threadIdx.x;
    if (e >= NE) return;
    int s = ei[e], d = ei[NE + e];
    if (s != d) atomicAdd(&rowcnt[d], 1);
}

// block-level inclusive scan -> exclusive out + per-block totals
__global__ void k_scanA(const int* __restrict__ in, int* __restrict__ out,
                        int* __restrict__ bsums) {
    __shared__ int s[1024];
    int tid = threadIdx.x;
    int gid = blockIdx.x * 1024 + tid;
    int v = in[gid];
    s[tid] = v;
    __syncthreads();
    for (int off = 1; off < 1024; off <<= 1) {
        int a = (tid >= off) ? s[tid - off] : 0;
        int cur = s[tid];
        __syncthreads();
        s[tid] = cur + a;
        __syncthreads();
    }
    out[gid] = s[tid] - v;                 // exclusive
    if (tid == 1023) bsums[blockIdx.x] = s[tid];
}

__global__ void k_scanB(int* __restrict__ bsums) {
    __shared__ int s[256];
    int tid = threadIdx.x;
    int v = (tid < SCAN_BLKS) ? bsums[tid] : 0;
    s[tid] = v;
    __syncthreads();
    for (int off = 1; off < 256; off <<= 1) {
        int a = (tid >= off) ? s[tid - off] : 0;
        int cur = s[tid];
        __syncthreads();
        s[tid] = cur + a;
        __syncthreads();
    }
    if (tid < SCAN_BLKS) bsums[tid] = s[tid] - v;  // exclusive
}

__global__ void k_scanC(int* __restrict__ out, const int* __restrict__ bsums,
                        int* __restrict__ cursor) {
    int gid = blockIdx.x * 1024 + threadIdx.x;
    int v = out[gid] + bsums[blockIdx.x];
    out[gid] = v;
    if (gid < NN) cursor[gid] = v;
}

// inv_sqrt[n] = rsqrt(rowcnt[n] + 1)
__global__ void k_invs(const int* __restrict__ rowcnt, float* __restrict__ inv_sqrt) {
    int n = blockIdx.x * 256 + threadIdx.x;
    if (n >= NN) return;
    inv_sqrt[n] = rsqrtf((float)(rowcnt[n] + 1));
}

__global__ void k_scatter(const int* __restrict__ ei, int* __restrict__ cursor,
                          int* __restrict__ esrc) {
    int e = blockIdx.x * 256 + threadIdx.x;
    if (e >= NE) return;
    int s = ei[e], d = ei[NE + e];
    if (s == d) return;
    int pos = atomicAdd(&cursor[d], 1);
    esrc[pos] = s;
}

// ---------------- dense matmul: hws[n,32] = (X[n,K] @ W[K,32]) * inv_sqrt[n] ----------------
template <int K>
__global__ void k_mm(const float* __restrict__ X, const float* __restrict__ W,
                     const float* __restrict__ inv_sqrt, float* __restrict__ Y) {
    __shared__ float sx[8 * K];
    int row0 = blockIdx.x * 8;
    int tid = threadIdx.x;
    for (int i = tid; i < 8 * K; i += 256) {
        int row = row0 + i / K;
        sx[i] = (row < NN) ? X[row0 * K + i] : 0.0f;
    }
    __syncthreads();
    int r = tid >> 5, c = tid & 31;
    int row = row0 + r;
    if (row >= NN) return;
    float acc = 0.0f;
#pragma unroll 8
    for (int k = 0; k < K; k++) acc = fmaf(sx[r * K + k], W[k * 32 + c], acc);
    Y[row * 32 + c] = acc * inv_sqrt[row];
}

// gather-aggregate + self-loop + bias + tanh, 32 channels/node
__global__ void k_aggr(const int* __restrict__ rowstart, const int* __restrict__ esrc,
                       const float* __restrict__ hws, const float* __restrict__ inv_sqrt,
                       const float* __restrict__ b, float* __restrict__ xout) {
    int t = blockIdx.x * 256 + threadIdx.x;
    int n = t >> 5, c = t & 31;
    if (n >= NN) return;
    int e0 = rowstart[n], e1 = rowstart[n + 1];
    float acc = hws[n * 32 + c];
    int e = e0;
    for (; e + 1 < e1; e += 2) {
        int s0 = esrc[e], s1 = esrc[e + 1];
        float v0 = hws[s0 * 32 + c];
        float v1 = hws[s1 * 32 + c];
        acc += v0;
        acc += v1;
    }
    if (e < e1) acc += hws[esrc[e] * 32 + c];
    xout[t] = tanhf(fmaf(acc, inv_sqrt[n], b[c]));
}

// layer 4: hws4[n] = (x3[n,:] . W4) * inv_sqrt[n]
__global__ void k_mm4(const float* __restrict__ x3, const float* __restrict__ W4,
                      const float* __restrict__ inv_sqrt, float* __restrict__ hws4) {
    int n = blockIdx.x * 256 + threadIdx.x;
    if (n >= NN) return;
    const float4* xr = (const float4*)(x3 + n * 32);
    float acc = 0.0f;
#pragma unroll
    for (int q = 0; q < 8; q++) {
        float4 v = xr[q];
        acc = fmaf(v.x, W4[q * 4 + 0], acc);
        acc = fmaf(v.y, W4[q * 4 + 1], acc);
        acc = fmaf(v.z, W4[q * 4 + 2], acc);
        acc = fmaf(v.w, W4[q * 4 + 3], acc);
    }
    hws4[n] = acc * inv_sqrt[n];
}

__global__ void k_aggr1(const int* __restrict__ rowstart, const int* __restrict__ esrc,
                        const float* __restrict__ hws4, const float* __restrict__ inv_sqrt,
                        const float* __restrict__ b4, float* __restrict__ x4) {
    int n = blockIdx.x * 256 + threadIdx.x;
    if (n >= NN) return;
    int e0 = rowstart[n], e1 = rowstart[n + 1];
    float acc = hws4[n];
    int e = e0;
    for (; e + 1 < e1; e += 2) {
        float v0 = hws4[esrc[e]];
        float v1 = hws4[esrc[e + 1]];
        acc += v0;
        acc += v1;
    }
    if (e < e1) acc += hws4[esrc[e]];
    x4[n] = tanhf(fmaf(acc, inv_sqrt[n], b4[0]));
}

// ---------------- sort-pool ----------------
__global__ void k_hist(const int* __restrict__ batch, int* __restrict__ counts) {
    int n = blockIdx.x * 256 + threadIdx.x;
    if (n < NN) atomicAdd(&counts[batch[n]], 1);
}

__global__ void k_gscan(const int* __restrict__ counts, int* __restrict__ starts) {
    __shared__ int s[1024];
    int tid = threadIdx.x;
    int c = (tid < NG) ? counts[tid] : 0;
    s[tid] = c;
    __syncthreads();
    for (int off = 1; off < 1024; off <<= 1) {
        int v = s[tid];
        int a = (tid >= off) ? s[tid - off] : 0;
        __syncthreads();
        s[tid] = v + a;
        __syncthreads();
    }
    if (tid < NG) starts[tid] = s[tid] - c;
}

__global__ void k_sortpool(const int* __restrict__ starts, const int* __restrict__ counts,
                           const float* __restrict__ x1, const float* __restrict__ x2,
                           const float* __restrict__ x3, const float* __restrict__ x4,
                           float* __restrict__ pooled) {
    __shared__ float keys[1024];
    __shared__ int sel[KSEL];
    int g = blockIdx.x;
    int tid = threadIdx.x;
    int start = starts[g];
    int cnt = counts[g];
    if (cnt > 1024) cnt = 1024;
    for (int i = tid; i < cnt; i += 256) keys[i] = x4[start + i];
    __syncthreads();
    for (int i = tid; i < cnt; i += 256) {
        float ki = keys[i];
        int rank = 0;
        for (int j = 0; j < cnt; j++) {
            float kj = keys[j];
            rank += (kj > ki) || (kj == ki && j < i);  // stable desc, matches lexsort
        }
        if (rank < KSEL) sel[rank] = start + i;
    }
    __syncthreads();
    int selcnt = cnt < KSEL ? cnt : KSEL;
    for (int t = tid; t < KSEL * CCAT; t += 256) {
        int r = t / CCAT, ch = t - r * CCAT;
        float v = 0.0f;
        if (r < selcnt) {
            int node = sel[r];
            if (ch < 32)      v = x1[node * 32 + ch];
            else if (ch < 64) v = x2[node * 32 + ch - 32];
            else if (ch < 96) v = x3[node * 32 + ch - 64];
            else              v = x4[node];
        }
        pooled[g * (KSEL * CCAT) + t] = v;
    }
}

// ---------------- CNN + MLP head, one block per graph ----------------
__global__ void k_head(const float* __restrict__ pooled,
                       const float* __restrict__ w5, const float* __restrict__ b5,
                       const float* __restrict__ w6, const float* __restrict__ b6,
                       const float* __restrict__ fw1, const float* __restrict__ fb1,
                       const float* __restrict__ fw2, const float* __restrict__ fb2,
                       float* __restrict__ out) {
    __shared__ float sP[KSEL * CCAT];
    __shared__ float s5[16 * 30];
    __shared__ float smp[16 * 15];
    __shared__ float sz[352];
    __shared__ float sh[128];
    __shared__ float sl[10];
    int g = blockIdx.x;
    int tid = threadIdx.x;
    for (int i = tid; i < KSEL * CCAT; i += 256) sP[i] = pooled[g * (KSEL * CCAT) + i];
    __syncthreads();
    for (int t = tid; t < 16 * 30; t += 256) {
        int c = t / 30, j = t - c * 30;
        float acc = b5[c];
        for (int i = 0; i < CCAT; i++) acc = fmaf(sP[j * CCAT + i], w5[c * CCAT + i], acc);
        s5[c * 30 + j] = fmaxf(acc, 0.0f);
    }
    __syncthreads();
    for (int t = tid; t < 16 * 15; t += 256) {
        int c = t / 15, j = t - c * 15;
        smp[t] = fmaxf(s5[c * 30 + 2 * j], s5[c * 30 + 2 * j + 1]);
    }
    __syncthreads();
    for (int t = tid; t < 32 * 11; t += 256) {
        int c = t / 11, j = t - c * 11;
        float acc = b6[c];
        for (int ci = 0; ci < 16; ci++) {
#pragma unroll
            for (int k = 0; k < 5; k++)
                acc = fmaf(smp[ci * 15 + j + k], w6[(c * 16 + ci) * 5 + k], acc);
        }
        sz[t] = fmaxf(acc, 0.0f);
    }
    __syncthreads();
    if (tid < 128) {
        float acc = fb1[tid];
        for (int i = 0; i < 352; i++) acc = fmaf(sz[i], fw1[i * 128 + tid], acc);
        sh[tid] = fmaxf(acc, 0.0f);
    }
    __syncthreads();
    if (tid < 10) {
        float acc = fb2[tid];
        for (int i = 0; i < 128; i++) acc = fmaf(sh[i], fw2[i * 10 + tid], acc);
        sl[tid] = acc;
    }
    __syncthreads();
    if (tid < 10) {
        float m = -1e30f;
        for (int i = 0; i < 10; i++) m = fmaxf(m, sl[i]);
        float ssum = 0.0f;
        for (int i = 0; i < 10; i++) ssum += expf(sl[i] - m);
        out[g * 10 + tid] = sl[tid] - m - logf(ssum);
    }
}

extern "C" void kernel_launch(void* const* d_in, const int* in_sizes, int n_in,
                              void* d_out, int out_size, void* d_ws, size_t ws_size,
                              hipStream_t stream) {
    const float* x   = (const float*)d_in[0];
    const int*   ei  = (const int*)d_in[1];
    const int*   bat = (const int*)d_in[2];
    const float* W1  = (const float*)d_in[3];
    const float* b1  = (const float*)d_in[4];
    const float* W2  = (const float*)d_in[5];
    const float* b2  = (const float*)d_in[6];
    const float* W3  = (const float*)d_in[7];
    const float* b3  = (const float*)d_in[8];
    const float* W4  = (const float*)d_in[9];
    const float* b4  = (const float*)d_in[10];
    const float* w5  = (const float*)d_in[11];
    const float* b5  = (const float*)d_in[12];
    const float* w6  = (const float*)d_in[13];
    const float* b6  = (const float*)d_in[14];
    const float* fw1 = (const float*)d_in[15];
    const float* fb1 = (const float*)d_in[16];
    const float* fw2 = (const float*)d_in[17];
    const float* fb2 = (const float*)d_in[18];
    float* out = (float*)d_out;

    float* ws = (float*)d_ws;
    float* inv_sqrt = ws;                          // NN
    float* hws      = inv_sqrt + NN;               // NN*32 (also hws4 in first NN)
    float* x1       = hws + NN * 32;               // NN*32
    float* x2       = x1 + NN * 32;                // NN*32
    float* x3       = x2 + NN * 32;                // NN*32
    float* x4       = x3 + NN * 32;                // NN
    float* pooled   = x4 + NN;                     // NG*KSEL*CCAT
    int* rowcnt     = (int*)(pooled + NG * KSEL * CCAT);  // NPAD
    int* rowstart   = rowcnt + NPAD;               // NPAD
    int* cursor     = rowstart + NPAD;             // NN
    int* esrc       = cursor + NN;                 // NE
    int* bsums      = esrc + NE;                   // 256
    int* gcounts    = bsums + 256;                 // 1024
    int* gstarts    = gcounts + 1024;              // 1024

    const int TB = 256;
    int gN  = (NN + TB - 1) / TB;
    int gE  = (NE + TB - 1) / TB;
    int gNC = (NN * 32 + TB - 1) / TB;
    int gMM = (NN + 7) / 8;

    // ---- CSR build (in-edges by dst, self-loops removed) ----
    hipMemsetAsync(rowcnt, 0, NPAD * sizeof(int), stream);
    k_degcnt<<<gE, TB, 0, stream>>>(ei, rowcnt);
    k_scanA<<<SCAN_BLKS, 1024, 0, stream>>>(rowcnt, rowstart, bsums);
    k_scanB<<<1, 256, 0, stream>>>(bsums);
    k_scanC<<<SCAN_BLKS, 1024, 0, stream>>>(rowstart, bsums, cursor);
    k_invs<<<gN, TB, 0, stream>>>(rowcnt, inv_sqrt);
    k_scatter<<<gE, TB, 0, stream>>>(ei, cursor, esrc);

    // ---- graph histogram/offsets (independent) ----
    hipMemsetAsync(gcounts, 0, 1024 * sizeof(int), stream);
    k_hist<<<gN, TB, 0, stream>>>(bat, gcounts);
    k_gscan<<<1, 1024, 0, stream>>>(gcounts, gstarts);

    // ---- GCN layers ----
    k_mm<128><<<gMM, TB, 0, stream>>>(x, W1, inv_sqrt, hws);
    k_aggr<<<gNC / 1, TB, 0, stream>>>(rowstart, esrc, hws, inv_sqrt, b1, x1);
    k_mm<32><<<gMM, TB, 0, stream>>>(x1, W2, inv_sqrt, hws);
    k_aggr<<<gNC, TB, 0, stream>>>(rowstart, esrc, hws, inv_sqrt, b2, x2);
    k_mm<32><<<gMM, TB, 0, stream>>>(x2, W3, inv_sqrt, hws);
    k_aggr<<<gNC, TB, 0, stream>>>(rowstart, esrc, hws, inv_sqrt, b3, x3);
    k_mm4<<<gN, TB, 0, stream>>>(x3, W4, inv_sqrt, hws);
    k_aggr1<<<gN, TB, 0, stream>>>(rowstart, esrc, hws, inv_sqrt, b4, x4);

    // ---- sort-pool + head ----
    k_sortpool<<<NG, TB, 0, stream>>>(gstarts, gcounts, x1, x2, x3, x4, pooled);
    k_head<<<NG, TB, 0, stream>>>(pooled, w5, b5, w6, b6, fw1, fb1, fw2, fb2, out);
}

// Round 3
// 945.396 us; speedup vs baseline: 2.1315x; 1.3338x over previous
//
#include <hip/hip_runtime.h>
#include <math.h>

#define NN 200000
#define NE 3200000
#define NF 128
#define NG 1000
#define KSEL 30
#define CCAT 97
#define NPAD 200704      // 196 * 1024, padded node count for the scan
#define SCAN_BLKS 196

#define BWID 512                  // nodes per bucket (dst >> 9)
#define NB 391                    // ceil(NN / BWID)
#define BCAP 10240                // per-bucket edge capacity (mean 8184, sigma ~90)
#define P1_CHUNK 8192             // edges per block in partition pass
#define P1_BLKS 391               // ceil(NE / P1_CHUNK)

// ---------------- pass 1: partition edges into dst-buckets ----------------
__global__ void k_p1_partition(const int* __restrict__ ei, int* __restrict__ bcursor,
                               int* __restrict__ ebuf) {
    __shared__ int lhist[NB];
    __shared__ int lbase[NB];
    int tid = threadIdx.x;
    int base = blockIdx.x * P1_CHUNK;
    for (int b = tid; b < NB; b += 256) lhist[b] = 0;
    __syncthreads();
    // phase A: local histogram
    for (int it = 0; it < P1_CHUNK / 256; it++) {
        int e = base + it * 256 + tid;
        if (e < NE) {
            int s = ei[e], d = ei[NE + e];
            if (s != d) atomicAdd(&lhist[d >> 9], 1);
        }
    }
    __syncthreads();
    // phase B: reserve global space per bucket, reset local counters
    for (int b = tid; b < NB; b += 256) {
        int cnt = lhist[b];
        lbase[b] = cnt ? atomicAdd(&bcursor[b], cnt) : 0;
        lhist[b] = 0;
    }
    __syncthreads();
    // phase C: write packed edges (src | local<<18), src<2^18, local<2^9
    for (int it = 0; it < P1_CHUNK / 256; it++) {
        int e = base + it * 256 + tid;
        if (e < NE) {
            int s = ei[e], d = ei[NE + e];
            if (s != d) {
                int b = d >> 9;
                int r = atomicAdd(&lhist[b], 1);
                int pos = lbase[b] + r;
                if (pos >= BCAP) pos = BCAP - 1;  // defensive (cannot happen)
                ebuf[b * BCAP + pos] = s | ((d & 511) << 18);
            }
        }
    }
}

// ---------------- pass 2: per-bucket node counts (coalesced) + inv_sqrt ----------------
__global__ void k_p2_count(const int* __restrict__ bcursor, const int* __restrict__ ebuf,
                           int* __restrict__ rowcnt, float* __restrict__ inv_sqrt) {
    __shared__ int lcnt[BWID];
    int b = blockIdx.x;
    int tid = threadIdx.x;
    for (int i = tid; i < BWID; i += 256) lcnt[i] = 0;
    __syncthreads();
    int size = bcursor[b];
    if (size > BCAP) size = BCAP;
    const int* eb = ebuf + b * BCAP;
    for (int k = tid; k < size; k += 256) atomicAdd(&lcnt[eb[k] >> 18], 1);
    __syncthreads();
    int node0 = b * BWID;
    for (int i = tid; i < BWID; i += 256) {
        int node = node0 + i;
        if (node < NN) {
            int c = lcnt[i];
            rowcnt[node] = c;
            inv_sqrt[node] = rsqrtf((float)(c + 1));
        }
    }
}

// ---------------- scan (rowcnt -> rowstart, exclusive) ----------------
__global__ void k_scanA(const int* __restrict__ in, int* __restrict__ out,
                        int* __restrict__ bsums) {
    __shared__ int s[1024];
    int tid = threadIdx.x;
    int gid = blockIdx.x * 1024 + tid;
    int v = in[gid];
    s[tid] = v;
    __syncthreads();
    for (int off = 1; off < 1024; off <<= 1) {
        int a = (tid >= off) ? s[tid - off] : 0;
        int cur = s[tid];
        __syncthreads();
        s[tid] = cur + a;
        __syncthreads();
    }
    out[gid] = s[tid] - v;
    if (tid == 1023) bsums[blockIdx.x] = s[tid];
}

__global__ void k_scanB(int* __restrict__ bsums) {
    __shared__ int s[256];
    int tid = threadIdx.x;
    int v = (tid < SCAN_BLKS) ? bsums[tid] : 0;
    s[tid] = v;
    __syncthreads();
    for (int off = 1; off < 256; off <<= 1) {
        int a = (tid >= off) ? s[tid - off] : 0;
        int cur = s[tid];
        __syncthreads();
        s[tid] = cur + a;
        __syncthreads();
    }
    if (tid < SCAN_BLKS) bsums[tid] = s[tid] - v;
}

__global__ void k_scanC(int* __restrict__ out, const int* __restrict__ bsums) {
    int gid = blockIdx.x * 1024 + threadIdx.x;
    out[gid] += bsums[blockIdx.x];
}

// ---------------- pass 3: bucket -> CSR esrc (writes localized per block) ----------------
__global__ void k_p3_scatter(const int* __restrict__ bcursor, const int* __restrict__ ebuf,
                             const int* __restrict__ rowstart, int* __restrict__ esrc) {
    __shared__ int lcur[BWID];
    int b = blockIdx.x;
    int tid = threadIdx.x;
    int node0 = b * BWID;
    for (int i = tid; i < BWID; i += 256) lcur[i] = rowstart[node0 + i];
    __syncthreads();
    int size = bcursor[b];
    if (size > BCAP) size = BCAP;
    const int* eb = ebuf + b * BCAP;
    for (int k = tid; k < size; k += 256) {
        int v = eb[k];
        int local = v >> 18;
        int pos = atomicAdd(&lcur[local], 1);
        esrc[pos] = v & 0x3FFFF;
    }
}

// ---------------- dense matmul: hws[n,32] = (X[n,K] @ W[K,32]) * inv_sqrt[n] ----------------
template <int K>
__global__ void k_mm(const float* __restrict__ X, const float* __restrict__ W,
                     const float* __restrict__ inv_sqrt, float* __restrict__ Y) {
    __shared__ float sx[8 * K];
    int row0 = blockIdx.x * 8;
    int tid = threadIdx.x;
    for (int i = tid; i < 8 * K; i += 256) {
        int row = row0 + i / K;
        sx[i] = (row < NN) ? X[row0 * K + i] : 0.0f;
    }
    __syncthreads();
    int r = tid >> 5, c = tid & 31;
    int row = row0 + r;
    if (row >= NN) return;
    float acc = 0.0f;
#pragma unroll 8
    for (int k = 0; k < K; k++) acc = fmaf(sx[r * K + k], W[k * 32 + c], acc);
    Y[row * 32 + c] = acc * inv_sqrt[row];
}

// gather-aggregate + self-loop + bias + tanh, 32 channels/node
__global__ void k_aggr(const int* __restrict__ rowstart, const int* __restrict__ esrc,
                       const float* __restrict__ hws, const float* __restrict__ inv_sqrt,
                       const float* __restrict__ b, float* __restrict__ xout) {
    int t = blockIdx.x * 256 + threadIdx.x;
    int n = t >> 5, c = t & 31;
    if (n >= NN) return;
    int e0 = rowstart[n], e1 = rowstart[n + 1];
    float acc = hws[n * 32 + c];
    int e = e0;
    for (; e + 1 < e1; e += 2) {
        int s0 = esrc[e], s1 = esrc[e + 1];
        float v0 = hws[s0 * 32 + c];
        float v1 = hws[s1 * 32 + c];
        acc += v0;
        acc += v1;
    }
    if (e < e1) acc += hws[esrc[e] * 32 + c];
    xout[t] = tanhf(fmaf(acc, inv_sqrt[n], b[c]));
}

// layer 4: hws4[n] = (x3[n,:] . W4) * inv_sqrt[n]
__global__ void k_mm4(const float* __restrict__ x3, const float* __restrict__ W4,
                      const float* __restrict__ inv_sqrt, float* __restrict__ hws4) {
    int n = blockIdx.x * 256 + threadIdx.x;
    if (n >= NN) return;
    const float4* xr = (const float4*)(x3 + n * 32);
    float acc = 0.0f;
#pragma unroll
    for (int q = 0; q < 8; q++) {
        float4 v = xr[q];
        acc = fmaf(v.x, W4[q * 4 + 0], acc);
        acc = fmaf(v.y, W4[q * 4 + 1], acc);
        acc = fmaf(v.z, W4[q * 4 + 2], acc);
        acc = fmaf(v.w, W4[q * 4 + 3], acc);
    }
    hws4[n] = acc * inv_sqrt[n];
}

__global__ void k_aggr1(const int* __restrict__ rowstart, const int* __restrict__ esrc,
                        const float* __restrict__ hws4, const float* __restrict__ inv_sqrt,
                        const float* __restrict__ b4, float* __restrict__ x4) {
    int n = blockIdx.x * 256 + threadIdx.x;
    if (n >= NN) return;
    int e0 = rowstart[n], e1 = rowstart[n + 1];
    float acc = hws4[n];
    int e = e0;
    for (; e + 1 < e1; e += 2) {
        float v0 = hws4[esrc[e]];
        float v1 = hws4[esrc[e + 1]];
        acc += v0;
        acc += v1;
    }
    if (e < e1) acc += hws4[esrc[e]];
    x4[n] = tanhf(fmaf(acc, inv_sqrt[n], b4[0]));
}

// ---------------- sort-pool ----------------
__global__ void k_hist(const int* __restrict__ batch, int* __restrict__ counts) {
    int n = blockIdx.x * 256 + threadIdx.x;
    if (n < NN) atomicAdd(&counts[batch[n]], 1);
}

__global__ void k_gscan(const int* __restrict__ counts, int* __restrict__ starts) {
    __shared__ int s[1024];
    int tid = threadIdx.x;
    int c = (tid < NG) ? counts[tid] : 0;
    s[tid] = c;
    __syncthreads();
    for (int off = 1; off < 1024; off <<= 1) {
        int v = s[tid];
        int a = (tid >= off) ? s[tid - off] : 0;
        __syncthreads();
        s[tid] = v + a;
        __syncthreads();
    }
    if (tid < NG) starts[tid] = s[tid] - c;
}

__global__ void k_sortpool(const int* __restrict__ starts, const int* __restrict__ counts,
                           const float* __restrict__ x1, const float* __restrict__ x2,
                           const float* __restrict__ x3, const float* __restrict__ x4,
                           float* __restrict__ pooled) {
    __shared__ float keys[1024];
    __shared__ int sel[KSEL];
    int g = blockIdx.x;
    int tid = threadIdx.x;
    int start = starts[g];
    int cnt = counts[g];
    if (cnt > 1024) cnt = 1024;
    for (int i = tid; i < cnt; i += 256) keys[i] = x4[start + i];
    __syncthreads();
    for (int i = tid; i < cnt; i += 256) {
        float ki = keys[i];
        int rank = 0;
        for (int j = 0; j < cnt; j++) {
            float kj = keys[j];
            rank += (kj > ki) || (kj == ki && j < i);  // stable desc, matches lexsort
        }
        if (rank < KSEL) sel[rank] = start + i;
    }
    __syncthreads();
    int selcnt = cnt < KSEL ? cnt : KSEL;
    for (int t = tid; t < KSEL * CCAT; t += 256) {
        int r = t / CCAT, ch = t - r * CCAT;
        float v = 0.0f;
        if (r < selcnt) {
            int node = sel[r];
            if (ch < 32)      v = x1[node * 32 + ch];
            else if (ch < 64) v = x2[node * 32 + ch - 32];
            else if (ch < 96) v = x3[node * 32 + ch - 64];
            else              v = x4[node];
        }
        pooled[g * (KSEL * CCAT) + t] = v;
    }
}

// ---------------- CNN + MLP head, one block per graph ----------------
__global__ void k_head(const float* __restrict__ pooled,
                       const float* __restrict__ w5, const float* __restrict__ b5,
                       const float* __restrict__ w6, const float* __restrict__ b6,
                       const float* __restrict__ fw1, const float* __restrict__ fb1,
                       const float* __restrict__ fw2, const float* __restrict__ fb2,
                       float* __restrict__ out) {
    __shared__ float sP[KSEL * CCAT];
    __shared__ float s5[16 * 30];
    __shared__ float smp[16 * 15];
    __shared__ float sz[352];
    __shared__ float sh[128];
    __shared__ float sl[10];
    int g = blockIdx.x;
    int tid = threadIdx.x;
    for (int i = tid; i < KSEL * CCAT; i += 256) sP[i] = pooled[g * (KSEL * CCAT) + i];
    __syncthreads();
    for (int t = tid; t < 16 * 30; t += 256) {
        int c = t / 30, j = t - c * 30;
        float acc = b5[c];
        for (int i = 0; i < CCAT; i++) acc = fmaf(sP[j * CCAT + i], w5[c * CCAT + i], acc);
        s5[c * 30 + j] = fmaxf(acc, 0.0f);
    }
    __syncthreads();
    for (int t = tid; t < 16 * 15; t += 256) {
        int c = t / 15, j = t - c * 15;
        smp[t] = fmaxf(s5[c * 30 + 2 * j], s5[c * 30 + 2 * j + 1]);
    }
    __syncthreads();
    for (int t = tid; t < 32 * 11; t += 256) {
        int c = t / 11, j = t - c * 11;
        float acc = b6[c];
        for (int ci = 0; ci < 16; ci++) {
#pragma unroll
            for (int k = 0; k < 5; k++)
                acc = fmaf(smp[ci * 15 + j + k], w6[(c * 16 + ci) * 5 + k], acc);
        }
        sz[t] = fmaxf(acc, 0.0f);
    }
    __syncthreads();
    if (tid < 128) {
        float acc = fb1[tid];
        for (int i = 0; i < 352; i++) acc = fmaf(sz[i], fw1[i * 128 + tid], acc);
        sh[tid] = fmaxf(acc, 0.0f);
    }
    __syncthreads();
    if (tid < 10) {
        float acc = fb2[tid];
        for (int i = 0; i < 128; i++) acc = fmaf(sh[i], fw2[i * 10 + tid], acc);
        sl[tid] = acc;
    }
    __syncthreads();
    if (tid < 10) {
        float m = -1e30f;
        for (int i = 0; i < 10; i++) m = fmaxf(m, sl[i]);
        float ssum = 0.0f;
        for (int i = 0; i < 10; i++) ssum += expf(sl[i] - m);
        out[g * 10 + tid] = sl[tid] - m - logf(ssum);
    }
}

extern "C" void kernel_launch(void* const* d_in, const int* in_sizes, int n_in,
                              void* d_out, int out_size, void* d_ws, size_t ws_size,
                              hipStream_t stream) {
    const float* x   = (const float*)d_in[0];
    const int*   ei  = (const int*)d_in[1];
    const int*   bat = (const int*)d_in[2];
    const float* W1  = (const float*)d_in[3];
    const float* b1  = (const float*)d_in[4];
    const float* W2  = (const float*)d_in[5];
    const float* b2  = (const float*)d_in[6];
    const float* W3  = (const float*)d_in[7];
    const float* b3  = (const float*)d_in[8];
    const float* W4  = (const float*)d_in[9];
    const float* b4  = (const float*)d_in[10];
    const float* w5  = (const float*)d_in[11];
    const float* b5  = (const float*)d_in[12];
    const float* w6  = (const float*)d_in[13];
    const float* b6  = (const float*)d_in[14];
    const float* fw1 = (const float*)d_in[15];
    const float* fb1 = (const float*)d_in[16];
    const float* fw2 = (const float*)d_in[17];
    const float* fb2 = (const float*)d_in[18];
    float* out = (float*)d_out;

    float* ws = (float*)d_ws;
    float* inv_sqrt = ws;                          // NN
    float* hws      = inv_sqrt + NN;               // NN*32 (also hws4 in first NN)
    float* x1       = hws + NN * 32;               // NN*32
    float* x2       = x1 + NN * 32;                // NN*32
    float* x3       = x2 + NN * 32;                // NN*32
    float* x4       = x3 + NN * 32;                // NN
    float* pooled   = x4 + NN;                     // NG*KSEL*CCAT
    int* rowcnt     = (int*)(pooled + NG * KSEL * CCAT);  // NPAD
    int* rowstart   = rowcnt + NPAD;               // NPAD
    int* esrc       = rowstart + NPAD;             // NE
    int* bcursor    = esrc + NE;                   // NB (pad to 512)
    int* bsums      = bcursor + 512;               // 256
    int* gcounts    = bsums + 256;                 // 1024
    int* gstarts    = gcounts + 1024;              // 1024
    int* ebuf       = (int*)x3;                    // NB*BCAP ints (16 MB), dead before x3 written

    const int TB = 256;
    int gN  = (NN + TB - 1) / TB;
    int gNC = (NN * 32 + TB - 1) / TB;
    int gMM = (NN + 7) / 8;

    // ---- CSR build via bucketed partition ----
    hipMemsetAsync(bcursor, 0, 512 * sizeof(int), stream);
    hipMemsetAsync(rowcnt, 0, NPAD * sizeof(int), stream);
    k_p1_partition<<<P1_BLKS, TB, 0, stream>>>(ei, bcursor, ebuf);
    k_p2_count<<<NB, TB, 0, stream>>>(bcursor, ebuf, rowcnt, inv_sqrt);
    k_scanA<<<SCAN_BLKS, 1024, 0, stream>>>(rowcnt, rowstart, bsums);
    k_scanB<<<1, 256, 0, stream>>>(bsums);
    k_scanC<<<SCAN_BLKS, 1024, 0, stream>>>(rowstart, bsums);
    k_p3_scatter<<<NB, TB, 0, stream>>>(bcursor, ebuf, rowstart, esrc);

    // ---- graph histogram/offsets (independent) ----
    hipMemsetAsync(gcounts, 0, 1024 * sizeof(int), stream);
    k_hist<<<gN, TB, 0, stream>>>(bat, gcounts);
    k_gscan<<<1, 1024, 0, stream>>>(gcounts, gstarts);

    // ---- GCN layers ----
    k_mm<128><<<gMM, TB, 0, stream>>>(x, W1, inv_sqrt, hws);
    k_aggr<<<gNC, TB, 0, stream>>>(rowstart, esrc, hws, inv_sqrt, b1, x1);
    k_mm<32><<<gMM, TB, 0, stream>>>(x1, W2, inv_sqrt, hws);
    k_aggr<<<gNC, TB, 0, stream>>>(rowstart, esrc, hws, inv_sqrt, b2, x2);
    k_mm<32><<<gMM, TB, 0, stream>>>(x2, W3, inv_sqrt, hws);
    k_aggr<<<gNC, TB, 0, stream>>>(rowstart, esrc, hws, inv_sqrt, b3, x3);
    k_mm4<<<gN, TB, 0, stream>>>(x3, W4, inv_sqrt, hws);
    k_aggr1<<<gN, TB, 0, stream>>>(rowstart, esrc, hws, inv_sqrt, b4, x4);

    // ---- sort-pool + head ----
    k_sortpool<<<NG, TB, 0, stream>>>(gstarts, gcounts, x1, x2, x3, x4, pooled);
    k_head<<<NG, TB, 0, stream>>>(pooled, w5, b5, w6, b6, fw1, fb1, fw2, fb2, out);
}

// Round 4
// 843.516 us; speedup vs baseline: 2.3890x; 1.1208x over previous
//
#include <hip/hip_runtime.h>
#include <math.h>

#define NN 200000
#define NE 3200000
#define NF 128
#define NG 1000
#define KSEL 30
#define CCAT 97
#define NPAD 200704      // 196 * 1024, padded node count for the scan
#define SCAN_BLKS 196

#define BWID 512                  // nodes per bucket (dst >> 9)
#define NB 391                    // ceil(NN / BWID)
#define BCAP 10240                // per-bucket edge capacity (mean 8184, sigma ~90)
#define P1_CHUNK 8192             // edges per block in partition pass
#define P1_BLKS 391               // ceil(NE / P1_CHUNK)

// ---------------- pass 1: partition edges into dst-buckets ----------------
__global__ void k_p1_partition(const int* __restrict__ ei, int* __restrict__ bcursor,
                               int* __restrict__ ebuf) {
    __shared__ int lhist[NB];
    __shared__ int lbase[NB];
    int tid = threadIdx.x;
    int base = blockIdx.x * P1_CHUNK;
    for (int b = tid; b < NB; b += 256) lhist[b] = 0;
    __syncthreads();
    for (int it = 0; it < P1_CHUNK / 256; it++) {
        int e = base + it * 256 + tid;
        if (e < NE) {
            int s = ei[e], d = ei[NE + e];
            if (s != d) atomicAdd(&lhist[d >> 9], 1);
        }
    }
    __syncthreads();
    for (int b = tid; b < NB; b += 256) {
        int cnt = lhist[b];
        lbase[b] = cnt ? atomicAdd(&bcursor[b], cnt) : 0;
        lhist[b] = 0;
    }
    __syncthreads();
    for (int it = 0; it < P1_CHUNK / 256; it++) {
        int e = base + it * 256 + tid;
        if (e < NE) {
            int s = ei[e], d = ei[NE + e];
            if (s != d) {
                int b = d >> 9;
                int r = atomicAdd(&lhist[b], 1);
                int pos = lbase[b] + r;
                if (pos >= BCAP) pos = BCAP - 1;  // defensive (cannot happen)
                ebuf[b * BCAP + pos] = s | ((d & 511) << 18);
            }
        }
    }
}

// ---------------- pass 2: per-bucket node counts (coalesced) + inv_sqrt ----------------
__global__ void k_p2_count(const int* __restrict__ bcursor, const int* __restrict__ ebuf,
                           int* __restrict__ rowcnt, float* __restrict__ inv_sqrt) {
    __shared__ int lcnt[BWID];
    int b = blockIdx.x;
    int tid = threadIdx.x;
    for (int i = tid; i < BWID; i += 256) lcnt[i] = 0;
    __syncthreads();
    int size = bcursor[b];
    if (size > BCAP) size = BCAP;
    const int* eb = ebuf + b * BCAP;
    for (int k = tid; k < size; k += 256) atomicAdd(&lcnt[eb[k] >> 18], 1);
    __syncthreads();
    int node0 = b * BWID;
    for (int i = tid; i < BWID; i += 256) {
        int node = node0 + i;
        if (node < NN) {
            int c = lcnt[i];
            rowcnt[node] = c;
            inv_sqrt[node] = rsqrtf((float)(c + 1));
        }
    }
}

// ---------------- scan (rowcnt -> rowstart, exclusive) ----------------
__global__ void k_scanA(const int* __restrict__ in, int* __restrict__ out,
                        int* __restrict__ bsums) {
    __shared__ int s[1024];
    int tid = threadIdx.x;
    int gid = blockIdx.x * 1024 + tid;
    int v = in[gid];
    s[tid] = v;
    __syncthreads();
    for (int off = 1; off < 1024; off <<= 1) {
        int a = (tid >= off) ? s[tid - off] : 0;
        int cur = s[tid];
        __syncthreads();
        s[tid] = cur + a;
        __syncthreads();
    }
    out[gid] = s[tid] - v;
    if (tid == 1023) bsums[blockIdx.x] = s[tid];
}

__global__ void k_scanB(int* __restrict__ bsums) {
    __shared__ int s[256];
    int tid = threadIdx.x;
    int v = (tid < SCAN_BLKS) ? bsums[tid] : 0;
    s[tid] = v;
    __syncthreads();
    for (int off = 1; off < 256; off <<= 1) {
        int a = (tid >= off) ? s[tid - off] : 0;
        int cur = s[tid];
        __syncthreads();
        s[tid] = cur + a;
        __syncthreads();
    }
    if (tid < SCAN_BLKS) bsums[tid] = s[tid] - v;
}

__global__ void k_scanC(int* __restrict__ out, const int* __restrict__ bsums) {
    int gid = blockIdx.x * 1024 + threadIdx.x;
    out[gid] += bsums[blockIdx.x];
}

// ---------------- pass 3: bucket -> CSR esrc (writes localized per block) ----------------
__global__ void k_p3_scatter(const int* __restrict__ bcursor, const int* __restrict__ ebuf,
                             const int* __restrict__ rowstart, int* __restrict__ esrc) {
    __shared__ int lcur[BWID];
    int b = blockIdx.x;
    int tid = threadIdx.x;
    int node0 = b * BWID;
    for (int i = tid; i < BWID; i += 256) lcur[i] = rowstart[node0 + i];
    __syncthreads();
    int size = bcursor[b];
    if (size > BCAP) size = BCAP;
    const int* eb = ebuf + b * BCAP;
    for (int k = tid; k < size; k += 256) {
        int v = eb[k];
        int local = v >> 18;
        int pos = atomicAdd(&lcur[local], 1);
        esrc[pos] = v & 0x3FFFF;
    }
}

// ---------------- dense matmul: hws[n,32] = (X[n,K] @ W[K,32]) * inv_sqrt[n] ----------------
// one thread per row; W staged in LDS as float4; X read as float4 from global;
// 32 accumulators in VGPRs -> FMA-dominant instruction mix
template <int K>
__global__ void k_mm(const float* __restrict__ X, const float* __restrict__ W,
                     const float* __restrict__ inv_sqrt, float* __restrict__ Y) {
    __shared__ float4 sW[K * 8];   // sW[k*8+q] = W[k][4q..4q+3]
    int tid = threadIdx.x;
    for (int i = tid; i < K * 8; i += 256) sW[i] = ((const float4*)W)[i];
    __syncthreads();
    int row = blockIdx.x * 256 + tid;
    if (row >= NN) return;
    float s = inv_sqrt[row];
    const float4* xp = (const float4*)(X + (size_t)row * K);
    float4 acc[8];
#pragma unroll
    for (int q = 0; q < 8; q++) acc[q] = make_float4(0.f, 0.f, 0.f, 0.f);
#pragma unroll 2
    for (int k4 = 0; k4 < K / 4; k4++) {
        float4 xv = xp[k4];
        const float4* wk = &sW[k4 * 32];
#pragma unroll
        for (int kk = 0; kk < 4; kk++) {
            float xs = (kk == 0) ? xv.x : (kk == 1) ? xv.y : (kk == 2) ? xv.z : xv.w;
#pragma unroll
            for (int q = 0; q < 8; q++) {
                float4 w = wk[kk * 8 + q];
                acc[q].x = fmaf(xs, w.x, acc[q].x);
                acc[q].y = fmaf(xs, w.y, acc[q].y);
                acc[q].z = fmaf(xs, w.z, acc[q].z);
                acc[q].w = fmaf(xs, w.w, acc[q].w);
            }
        }
    }
    float4* yp = (float4*)(Y + (size_t)row * 32);
#pragma unroll
    for (int q = 0; q < 8; q++) {
        float4 v = acc[q];
        v.x *= s; v.y *= s; v.z *= s; v.w *= s;
        yp[q] = v;
    }
}

// gather-aggregate + self-loop + bias + tanh, 32 channels/node
__global__ void k_aggr(const int* __restrict__ rowstart, const int* __restrict__ esrc,
                       const float* __restrict__ hws, const float* __restrict__ inv_sqrt,
                       const float* __restrict__ b, float* __restrict__ xout) {
    int t = blockIdx.x * 256 + threadIdx.x;
    int n = t >> 5, c = t & 31;
    if (n >= NN) return;
    int e0 = rowstart[n], e1 = rowstart[n + 1];
    float acc = hws[n * 32 + c];
    int e = e0;
    for (; e + 1 < e1; e += 2) {
        int s0 = esrc[e], s1 = esrc[e + 1];
        float v0 = hws[s0 * 32 + c];
        float v1 = hws[s1 * 32 + c];
        acc += v0;
        acc += v1;
    }
    if (e < e1) acc += hws[esrc[e] * 32 + c];
    xout[t] = tanhf(fmaf(acc, inv_sqrt[n], b[c]));
}

// layer 4: hws4[n] = (x3[n,:] . W4) * inv_sqrt[n]
__global__ void k_mm4(const float* __restrict__ x3, const float* __restrict__ W4,
                      const float* __restrict__ inv_sqrt, float* __restrict__ hws4) {
    int n = blockIdx.x * 256 + threadIdx.x;
    if (n >= NN) return;
    const float4* xr = (const float4*)(x3 + n * 32);
    float acc = 0.0f;
#pragma unroll
    for (int q = 0; q < 8; q++) {
        float4 v = xr[q];
        acc = fmaf(v.x, W4[q * 4 + 0], acc);
        acc = fmaf(v.y, W4[q * 4 + 1], acc);
        acc = fmaf(v.z, W4[q * 4 + 2], acc);
        acc = fmaf(v.w, W4[q * 4 + 3], acc);
    }
    hws4[n] = acc * inv_sqrt[n];
}

__global__ void k_aggr1(const int* __restrict__ rowstart, const int* __restrict__ esrc,
                        const float* __restrict__ hws4, const float* __restrict__ inv_sqrt,
                        const float* __restrict__ b4, float* __restrict__ x4) {
    int n = blockIdx.x * 256 + threadIdx.x;
    if (n >= NN) return;
    int e0 = rowstart[n], e1 = rowstart[n + 1];
    float acc = hws4[n];
    int e = e0;
    for (; e + 1 < e1; e += 2) {
        float v0 = hws4[esrc[e]];
        float v1 = hws4[esrc[e + 1]];
        acc += v0;
        acc += v1;
    }
    if (e < e1) acc += hws4[esrc[e]];
    x4[n] = tanhf(fmaf(acc, inv_sqrt[n], b4[0]));
}

// ---------------- sort-pool ----------------
__global__ void k_hist(const int* __restrict__ batch, int* __restrict__ counts) {
    int n = blockIdx.x * 256 + threadIdx.x;
    if (n < NN) atomicAdd(&counts[batch[n]], 1);
}

__global__ void k_gscan(const int* __restrict__ counts, int* __restrict__ starts) {
    __shared__ int s[1024];
    int tid = threadIdx.x;
    int c = (tid < NG) ? counts[tid] : 0;
    s[tid] = c;
    __syncthreads();
    for (int off = 1; off < 1024; off <<= 1) {
        int v = s[tid];
        int a = (tid >= off) ? s[tid - off] : 0;
        __syncthreads();
        s[tid] = v + a;
        __syncthreads();
    }
    if (tid < NG) starts[tid] = s[tid] - c;
}

__global__ void k_sortpool(const int* __restrict__ starts, const int* __restrict__ counts,
                           const float* __restrict__ x1, const float* __restrict__ x2,
                           const float* __restrict__ x3, const float* __restrict__ x4,
                           float* __restrict__ pooled) {
    __shared__ float keys[1024];
    __shared__ int sel[KSEL];
    int g = blockIdx.x;
    int tid = threadIdx.x;
    int start = starts[g];
    int cnt = counts[g];
    if (cnt > 1024) cnt = 1024;
    for (int i = tid; i < cnt; i += 256) keys[i] = x4[start + i];
    __syncthreads();
    for (int i = tid; i < cnt; i += 256) {
        float ki = keys[i];
        int rank = 0;
        for (int j = 0; j < cnt; j++) {
            float kj = keys[j];
            rank += (kj > ki) || (kj == ki && j < i);  // stable desc, matches lexsort
        }
        if (rank < KSEL) sel[rank] = start + i;
    }
    __syncthreads();
    int selcnt = cnt < KSEL ? cnt : KSEL;
    for (int t = tid; t < KSEL * CCAT; t += 256) {
        int r = t / CCAT, ch = t - r * CCAT;
        float v = 0.0f;
        if (r < selcnt) {
            int node = sel[r];
            if (ch < 32)      v = x1[node * 32 + ch];
            else if (ch < 64) v = x2[node * 32 + ch - 32];
            else if (ch < 96) v = x3[node * 32 + ch - 64];
            else              v = x4[node];
        }
        pooled[g * (KSEL * CCAT) + t] = v;
    }
}

// ---------------- CNN + MLP head, one block per graph ----------------
__global__ void k_head(const float* __restrict__ pooled,
                       const float* __restrict__ w5, const float* __restrict__ b5,
                       const float* __restrict__ w6, const float* __restrict__ b6,
                       const float* __restrict__ fw1, const float* __restrict__ fb1,
                       const float* __restrict__ fw2, const float* __restrict__ fb2,
                       float* __restrict__ out) {
    __shared__ float sP[KSEL * CCAT];
    __shared__ float s5[16 * 30];
    __shared__ float smp[16 * 15];
    __shared__ float sz[352];
    __shared__ float sh[128];
    __shared__ float sl[10];
    int g = blockIdx.x;
    int tid = threadIdx.x;
    for (int i = tid; i < KSEL * CCAT; i += 256) sP[i] = pooled[g * (KSEL * CCAT) + i];
    __syncthreads();
    for (int t = tid; t < 16 * 30; t += 256) {
        int c = t / 30, j = t - c * 30;
        float acc = b5[c];
        for (int i = 0; i < CCAT; i++) acc = fmaf(sP[j * CCAT + i], w5[c * CCAT + i], acc);
        s5[c * 30 + j] = fmaxf(acc, 0.0f);
    }
    __syncthreads();
    for (int t = tid; t < 16 * 15; t += 256) {
        int c = t / 15, j = t - c * 15;
        smp[t] = fmaxf(s5[c * 30 + 2 * j], s5[c * 30 + 2 * j + 1]);
    }
    __syncthreads();
    for (int t = tid; t < 32 * 11; t += 256) {
        int c = t / 11, j = t - c * 11;
        float acc = b6[c];
        for (int ci = 0; ci < 16; ci++) {
#pragma unroll
            for (int k = 0; k < 5; k++)
                acc = fmaf(smp[ci * 15 + j + k], w6[(c * 16 + ci) * 5 + k], acc);
        }
        sz[t] = fmaxf(acc, 0.0f);
    }
    __syncthreads();
    if (tid < 128) {
        float acc = fb1[tid];
        for (int i = 0; i < 352; i++) acc = fmaf(sz[i], fw1[i * 128 + tid], acc);
        sh[tid] = fmaxf(acc, 0.0f);
    }
    __syncthreads();
    if (tid < 10) {
        float acc = fb2[tid];
        for (int i = 0; i < 128; i++) acc = fmaf(sh[i], fw2[i * 10 + tid], acc);
        sl[tid] = acc;
    }
    __syncthreads();
    if (tid < 10) {
        float m = -1e30f;
        for (int i = 0; i < 10; i++) m = fmaxf(m, sl[i]);
        float ssum = 0.0f;
        for (int i = 0; i < 10; i++) ssum += expf(sl[i] - m);
        out[g * 10 + tid] = sl[tid] - m - logf(ssum);
    }
}

extern "C" void kernel_launch(void* const* d_in, const int* in_sizes, int n_in,
                              void* d_out, int out_size, void* d_ws, size_t ws_size,
                              hipStream_t stream) {
    const float* x   = (const float*)d_in[0];
    const int*   ei  = (const int*)d_in[1];
    const int*   bat = (const int*)d_in[2];
    const float* W1  = (const float*)d_in[3];
    const float* b1  = (const float*)d_in[4];
    const float* W2  = (const float*)d_in[5];
    const float* b2  = (const float*)d_in[6];
    const float* W3  = (const float*)d_in[7];
    const float* b3  = (const float*)d_in[8];
    const float* W4  = (const float*)d_in[9];
    const float* b4  = (const float*)d_in[10];
    const float* w5  = (const float*)d_in[11];
    const float* b5  = (const float*)d_in[12];
    const float* w6  = (const float*)d_in[13];
    const float* b6  = (const float*)d_in[14];
    const float* fw1 = (const float*)d_in[15];
    const float* fb1 = (const float*)d_in[16];
    const float* fw2 = (const float*)d_in[17];
    const float* fb2 = (const float*)d_in[18];
    float* out = (float*)d_out;

    float* ws = (float*)d_ws;
    float* inv_sqrt = ws;                          // NN
    float* hws      = inv_sqrt + NN;               // NN*32 (also hws4 in first NN)
    float* x1       = hws + NN * 32;               // NN*32
    float* x2       = x1 + NN * 32;                // NN*32
    float* x3       = x2 + NN * 32;                // NN*32
    float* x4       = x3 + NN * 32;                // NN
    float* pooled   = x4 + NN;                     // NG*KSEL*CCAT
    int* rowcnt     = (int*)(pooled + NG * KSEL * CCAT);  // NPAD
    int* rowstart   = rowcnt + NPAD;               // NPAD
    int* esrc       = rowstart + NPAD;             // NE
    int* bcursor    = esrc + NE;                   // NB (pad to 512)
    int* bsums      = bcursor + 512;               // 256
    int* gcounts    = bsums + 256;                 // 1024
    int* gstarts    = gcounts + 1024;              // 1024
    int* ebuf       = (int*)x3;                    // NB*BCAP ints (16 MB), dead before x3 written

    const int TB = 256;
    int gN  = (NN + TB - 1) / TB;
    int gNC = (NN * 32 + TB - 1) / TB;

    // ---- CSR build via bucketed partition ----
    hipMemsetAsync(bcursor, 0, 512 * sizeof(int), stream);
    hipMemsetAsync(rowcnt, 0, NPAD * sizeof(int), stream);
    k_p1_partition<<<P1_BLKS, TB, 0, stream>>>(ei, bcursor, ebuf);
    k_p2_count<<<NB, TB, 0, stream>>>(bcursor, ebuf, rowcnt, inv_sqrt);
    k_scanA<<<SCAN_BLKS, 1024, 0, stream>>>(rowcnt, rowstart, bsums);
    k_scanB<<<1, 256, 0, stream>>>(bsums);
    k_scanC<<<SCAN_BLKS, 1024, 0, stream>>>(rowstart, bsums);
    k_p3_scatter<<<NB, TB, 0, stream>>>(bcursor, ebuf, rowstart, esrc);

    // ---- graph histogram/offsets (independent) ----
    hipMemsetAsync(gcounts, 0, 1024 * sizeof(int), stream);
    k_hist<<<gN, TB, 0, stream>>>(bat, gcounts);
    k_gscan<<<1, 1024, 0, stream>>>(gcounts, gstarts);

    // ---- GCN layers ----
    k_mm<128><<<gN, TB, 0, stream>>>(x, W1, inv_sqrt, hws);
    k_aggr<<<gNC, TB, 0, stream>>>(rowstart, esrc, hws, inv_sqrt, b1, x1);
    k_mm<32><<<gN, TB, 0, stream>>>(x1, W2, inv_sqrt, hws);
    k_aggr<<<gNC, TB, 0, stream>>>(rowstart, esrc, hws, inv_sqrt, b2, x2);
    k_mm<32><<<gN, TB, 0, stream>>>(x2, W3, inv_sqrt, hws);
    k_aggr<<<gNC, TB, 0, stream>>>(rowstart, esrc, hws, inv_sqrt, b3, x3);
    k_mm4<<<gN, TB, 0, stream>>>(x3, W4, inv_sqrt, hws);
    k_aggr1<<<gN, TB, 0, stream>>>(rowstart, esrc, hws, inv_sqrt, b4, x4);

    // ---- sort-pool + head ----
    k_sortpool<<<NG, TB, 0, stream>>>(gstarts, gcounts, x1, x2, x3, x4, pooled);
    k_head<<<NG, TB, 0, stream>>>(pooled, w5, b5, w6, b6, fw1, fb1, fw2, fb2, out);
}